// Round 1
// baseline (540.076 us; speedup 1.0000x reference)
//
#include <hip/hip_runtime.h>
#include <hip/hip_bf16.h>
#include <hip/hip_cooperative_groups.h>

namespace cg = cooperative_groups;

#define N_NODES 10000
#define DIM 512
#define NCLS 64
#define BM 64
#define BN 128
#define BK 64
#define ELLW 64
#define NTILES ((DIM / BN) * ((N_NODES + BM - 1) / BM))   // 4 * 157 = 628
#define XCONV_BLKS 2500
#define TRANS_BLKS 544                                     // 256 + 256 + 32

typedef __hip_bfloat16 bf16;
typedef unsigned short u16;
typedef __attribute__((ext_vector_type(8))) short short8;
typedef __attribute__((ext_vector_type(4))) float f32x4;

__device__ __forceinline__ float b2f(bf16 v) { return __bfloat162float(v); }
__device__ __forceinline__ float ldIn(const void* p, size_t i, int isb) {
    return isb ? b2f(((const bf16*)p)[i]) : ((const float*)p)[i];
}
__device__ __forceinline__ int getE(const int* ei, int is64, int flat) {
    return is64 ? ei[2 * (size_t)flat] : ei[flat];
}
__device__ __forceinline__ void load_lds16(const bf16* g, bf16* l) {
    __builtin_amdgcn_global_load_lds(
        (const __attribute__((address_space(1))) void*)g,
        (__attribute__((address_space(3))) void*)l, 16, 0, 0);
}

struct Args {
    const void *X, *W1, *b1, *W2, *b2, *Wc, *bc;
    const int* ei;
    int *cursor, *ell;
    bf16 *Xb, *Wt1, *Wt2, *Wtc, *B0, *B1;
    float* out;
    int E;
};

// ---- GEMM phase: C[M,DIM](bf16) = (A @ Bt^T) * rsqrt(deg[row]+1).
//      64x128 tile, BK=64. T2 swizzle: LDS dest linear (global_load_lds),
//      global SOURCE pre-swizzled with slot^=(row&7); ds_read slot applies
//      the same XOR -> uniform 8-lanes-per-16B-slot (conflict-free b128). ----
__device__ void gemm_phase(const bf16* __restrict__ A, const bf16* __restrict__ Bt,
                           bf16* __restrict__ C, const int* __restrict__ deg,
                           char* smraw, int bid, int nb, int t) {
    bf16* At  = (bf16*)smraw;              // 8 KB
    bf16* Bts = (bf16*)(smraw + BM * BK * 2);  // 16 KB
    int w = t >> 6, l = t & 63;
    int srow8 = l >> 3;                    // row-in-chunk 0..7
    int sk8b  = (((l & 7) ^ srow8) * 8);   // pre-swizzled source k-offset (bf16 elems)

    for (int tile = bid; tile < NTILES; tile += nb) {
        int bm = (tile >> 2) * BM, bn = (tile & 3) * BN;
        f32x4 acc[4][2] = {};

        for (int k0 = 0; k0 < DIM; k0 += BK) {
            __syncthreads();
            #pragma unroll
            for (int i = 0; i < 2; i++) {       // A: 8 chunks of 8 rows, 2 per wave
                int c = w * 2 + i;
                load_lds16(A + (size_t)(bm + c * 8 + srow8) * DIM + k0 + sk8b, &At[c * 512]);
            }
            #pragma unroll
            for (int i = 0; i < 4; i++) {       // B: 16 chunks, 4 per wave
                int c = w * 4 + i;
                load_lds16(Bt + (size_t)(bn + c * 8 + srow8) * DIM + k0 + sk8b, &Bts[c * 512]);
            }
            __syncthreads();

            #pragma unroll
            for (int kk = 0; kk < BK; kk += 32) {
                short8 af[4], bfr[2];
                int slot = (((kk >> 3) + (l >> 4)) ^ (l & 7)) * 8;  // swizzled read slot
                #pragma unroll
                for (int i = 0; i < 4; i++)
                    af[i] = *(const short8*)&At[(i * 16 + (l & 15)) * BK + slot];
                #pragma unroll
                for (int j = 0; j < 2; j++)
                    bfr[j] = *(const short8*)&Bts[(w * 32 + j * 16 + (l & 15)) * BK + slot];
                #pragma unroll
                for (int i = 0; i < 4; i++)
                    #pragma unroll
                    for (int j = 0; j < 2; j++)
                        acc[i][j] = __builtin_amdgcn_mfma_f32_16x16x32_bf16(
                                        af[i], bfr[j], acc[i][j], 0, 0, 0);
            }
        }

        // C/D map: col = lane&15, row = (lane>>4)*4 + reg
        int col = l & 15, rq = (l >> 4) * 4;
        #pragma unroll
        for (int i = 0; i < 4; i++) {
            #pragma unroll
            for (int r = 0; r < 4; r++) {
                int gm = bm + i * 16 + rq + r;
                if (gm >= N_NODES) continue;
                float rs = rsqrtf((float)deg[gm] + 1.0f);
                #pragma unroll
                for (int j = 0; j < 2; j++) {
                    int gn = bn + w * 32 + j * 16 + col;
                    C[(size_t)gm * DIM + gn] = __float2bfloat16(acc[i][j][r] * rs);
                }
            }
        }
    }
}

// ---- gather (ELL): one wave per dst; indices in wave registers ----
__device__ void gather_phase(const int* __restrict__ cursor, const int* __restrict__ ell,
                             const bf16* __restrict__ Hs, const void* __restrict__ bias,
                             int isb, bf16* __restrict__ Out, int relu,
                             int bid, int nb, int w, int lane) {
    for (int wid = bid * 4 + w; wid < N_NODES; wid += nb * 4) {
        int cnt0 = cursor[wid];
        int cnt = min(cnt0, ELLW);
        int idx = ell[wid * ELLW + lane];   // lane i holds edge-index i

        float acc[8];
        bf16 v[8];
        *(uint4*)v = *(const uint4*)(Hs + (size_t)wid * DIM + lane * 8);   // self-loop
        #pragma unroll
        for (int j = 0; j < 8; j++) acc[j] = b2f(v[j]);

        int e = 0;
        for (; e + 7 < cnt; e += 8) {
            bf16 r[8][8];
            #pragma unroll
            for (int b = 0; b < 8; b++) {
                int s = __shfl(idx, e + b, 64);
                *(uint4*)r[b] = *(const uint4*)(Hs + (size_t)s * DIM + lane * 8);
            }
            #pragma unroll
            for (int j = 0; j < 8; j++)
                acc[j] += ((b2f(r[0][j]) + b2f(r[1][j])) + (b2f(r[2][j]) + b2f(r[3][j])))
                        + ((b2f(r[4][j]) + b2f(r[5][j])) + (b2f(r[6][j]) + b2f(r[7][j])));
        }
        for (; e < cnt; e++) {
            int s = __shfl(idx, e, 64);
            *(uint4*)v = *(const uint4*)(Hs + (size_t)s * DIM + lane * 8);
            #pragma unroll
            for (int j = 0; j < 8; j++) acc[j] += b2f(v[j]);
        }

        float ds = rsqrtf((float)cnt0 + 1.0f);
        bf16 o[8];
        #pragma unroll
        for (int j = 0; j < 8; j++) {
            float val = acc[j] * ds + ldIn(bias, lane * 8 + j, isb);
            if (relu) val = fmaxf(val, 0.0f);
            o[j] = __float2bfloat16(val);
        }
        *(uint4*)(Out + (size_t)wid * DIM + lane * 8) = *(uint4*)o;
    }
}

// ---- fused classifier + bias + log-softmax: one wave per 16 rows ----
__device__ void cls_phase(const bf16* __restrict__ A, const bf16* __restrict__ Wct,
                          const void* __restrict__ bias, int isb, float* __restrict__ out,
                          int bid, int nb, int w, int l) {
    const int NG = (N_NODES + 15) / 16;   // 625
    for (int g = bid * 4 + w; g < NG; g += nb * 4) {
        int row0 = g * 16;
        int q = l >> 4, col15 = l & 15;

        f32x4 acc[4] = {};
        #pragma unroll 4
        for (int k0 = 0; k0 < DIM; k0 += 32) {
            short8 af = *(const short8*)&A[(size_t)(row0 + col15) * DIM + k0 + q * 8];
            #pragma unroll
            for (int j = 0; j < 4; j++) {
                short8 bfr = *(const short8*)&Wct[(size_t)(j * 16 + col15) * DIM + k0 + q * 8];
                acc[j] = __builtin_amdgcn_mfma_f32_16x16x32_bf16(af, bfr, acc[j], 0, 0, 0);
            }
        }

        float bcol[4];
        #pragma unroll
        for (int j = 0; j < 4; j++) bcol[j] = ldIn(bias, j * 16 + col15, isb);

        #pragma unroll
        for (int r = 0; r < 4; r++) {
            int row = row0 + q * 4 + r;
            float v[4];
            #pragma unroll
            for (int j = 0; j < 4; j++) v[j] = acc[j][r] + bcol[j];
            float m = fmaxf(fmaxf(v[0], v[1]), fmaxf(v[2], v[3]));
            #pragma unroll
            for (int o = 8; o > 0; o >>= 1) m = fmaxf(m, __shfl_xor(m, o, 64));
            float s = __expf(v[0] - m) + __expf(v[1] - m) + __expf(v[2] - m) + __expf(v[3] - m);
            #pragma unroll
            for (int o = 8; o > 0; o >>= 1) s += __shfl_xor(s, o, 64);
            float lse = m + __logf(s);
            if (row < N_NODES) {
                #pragma unroll
                for (int j = 0; j < 4; j++) {
                    out[(size_t)row * NCLS + j * 16 + col15] = v[j];
                    out[(size_t)N_NODES * NCLS + (size_t)row * NCLS + j * 16 + col15] = v[j] - lse;
                }
            }
        }
    }
}

// ---- cooperative mega-kernel: whole pipeline, 5 grid syncs, 1 dispatch ----
__global__ __launch_bounds__(256) void mega(Args a) {
    cg::grid_group grid = cg::this_grid();
    // LDS pool: max(GEMM 24576 B, transpose 32*33*4 = 4224 B)
    __shared__ __align__(16) char smraw[(BM + BN) * BK * 2];
    __shared__ int sflags[2];

    int t = threadIdx.x, bid = blockIdx.x, nb = gridDim.x;
    int w = t >> 6, l = t & 63;

    // per-block dtype sniff (replaces init_kernel; ~300 cycles, L2-broadcast)
    if (t < 64) {
        const u16* x16 = (const u16*)a.X;
        int cf = 0;
        #pragma unroll
        for (int j = 0; j < 4; j++) {
            int e = (x16[l * 4 + j] >> 7) & 0xFF;
            cf += (e >= 97 && e <= 157) ? 1 : 0;
        }
        #pragma unroll
        for (int o = 32; o > 0; o >>= 1) cf += __shfl_xor(cf, o, 64);
        int cz = (l < 32) ? ((a.ei[2 * l + 1] == 0) ? 1 : 0) : 0;
        #pragma unroll
        for (int o = 32; o > 0; o >>= 1) cz += __shfl_xor(cz, o, 64);
        if (l == 0) { sflags[0] = (cf >= 200) ? 1 : 0; sflags[1] = (cz >= 16) ? 1 : 0; }
    }
    __syncthreads();
    int isb = sflags[0], is64 = sflags[1];

    // ---- P0: x->bf16 | weight transposes | ELL build (cursor pre-zeroed by memset) ----
    int nell = (a.E + 255) >> 8;
    for (int u = bid; u < XCONV_BLKS + TRANS_BLKS + nell; u += nb) {
        if (u < XCONV_BLKS) {                       // x: 8 elems/thread
            int base = (u * 256 + t) * 8;
            bf16 o[8];
            if (isb) {
                *(uint4*)o = *(const uint4*)((const bf16*)a.X + base);
            } else {
                const float* Xf = (const float*)a.X + base;
                float4 v0 = *(const float4*)Xf, v1 = *(const float4*)(Xf + 4);
                o[0] = __float2bfloat16(v0.x); o[1] = __float2bfloat16(v0.y);
                o[2] = __float2bfloat16(v0.z); o[3] = __float2bfloat16(v0.w);
                o[4] = __float2bfloat16(v1.x); o[5] = __float2bfloat16(v1.y);
                o[6] = __float2bfloat16(v1.z); o[7] = __float2bfloat16(v1.w);
            }
            *(uint4*)&a.Xb[base] = *(uint4*)o;
        } else if (u < XCONV_BLKS + TRANS_BLKS) {   // W[K][N] -> Wt[N][K] (32x32 tiles)
            float (*tile)[33] = (float(*)[33])smraw;
            int bb = u - XCONV_BLKS;
            const void* W; bf16* Wt; int N;
            if (bb < 256)      { W = a.W1; Wt = a.Wt1; N = DIM; }
            else if (bb < 512) { W = a.W2; Wt = a.Wt2; N = DIM;  bb -= 256; }
            else               { W = a.Wc; Wt = a.Wtc; N = NCLS; bb -= 512; }
            int nt = N / 32;
            int n0 = (bb % nt) * 32, k0 = (bb / nt) * 32;
            int tx = t & 31, ty = t >> 5;
            __syncthreads();      // protect tile from previous grid-stride iteration
            for (int r = ty; r < 32; r += 8)
                tile[r][tx] = ldIn(W, (size_t)(k0 + r) * N + n0 + tx, isb);
            __syncthreads();
            for (int r = ty; r < 32; r += 8)
                Wt[(size_t)(n0 + r) * DIM + k0 + tx] = __float2bfloat16(tile[tx][r]);
        } else {                                    // ELL build: one atomic per edge
            int e = (u - XCONV_BLKS - TRANS_BLKS) * 256 + t;
            if (e < a.E) {
                int s = getE(a.ei, is64, e), d = getE(a.ei, is64, a.E + e);
                if (!(s == d || (unsigned)s >= N_NODES || (unsigned)d >= N_NODES)) {
                    int pos = atomicAdd(&a.cursor[d], 1);
                    a.ell[d * ELLW + (pos & (ELLW - 1))] = s;
                }
            }
        }
    }

    __threadfence();  grid.sync();
    gemm_phase(a.Xb, a.Wt1, a.B0, a.cursor, smraw, bid, nb, t);
    __threadfence();  grid.sync();
    gather_phase(a.cursor, a.ell, a.B0, a.b1, isb, a.B1, 1, bid, nb, w, l);
    __threadfence();  grid.sync();
    gemm_phase(a.B1, a.Wt2, a.B0, a.cursor, smraw, bid, nb, t);
    __threadfence();  grid.sync();
    gather_phase(a.cursor, a.ell, a.B0, a.b2, isb, a.B1, 0, bid, nb, w, l);
    __threadfence();  grid.sync();
    cls_phase(a.B1, a.Wtc, a.bc, isb, a.out, bid, nb, w, l);
}

extern "C" void kernel_launch(void* const* d_in, const int* in_sizes, int n_in,
                              void* d_out, int out_size, void* d_ws, size_t ws_size,
                              hipStream_t stream) {
    char* ws = (char*)d_ws;
    Args a;
    a.X  = d_in[0];
    a.ei = (const int*)d_in[1];
    a.W1 = d_in[2]; a.b1 = d_in[3];
    a.W2 = d_in[4]; a.b2 = d_in[5];
    a.Wc = d_in[6]; a.bc = d_in[7];
    a.out = (float*)d_out;
    a.E = in_sizes[1] / 2;

    // workspace layout (~38 MB; A-operand buffers padded to 10240 rows)
    a.cursor = (int*) (ws + 65536);      // 40 KB
    a.ell    = (int*) (ws + 131072);     // 2.56 MB
    a.Xb     = (bf16*)(ws + 4194304);    // 10240 rows x 512 bf16
    a.Wt1    = (bf16*)(ws + 14680064);   // 512 KB
    a.Wt2    = (bf16*)(ws + 15204352);   // 512 KB
    a.Wtc    = (bf16*)(ws + 15728640);   // 64 KB
    a.B0     = (bf16*)(ws + 16777216);   // 10240 rows
    a.B1     = (bf16*)(ws + 27262976);   // 10240 rows

    hipMemsetAsync(a.cursor, 0, N_NODES * sizeof(int), stream);

    // co-residency-safe grid for cooperative launch
    static int maxb = 0;
    if (maxb == 0) {
        if (hipOccupancyMaxActiveBlocksPerMultiprocessor(&maxb, mega, 256, 0) != hipSuccess
            || maxb < 1)
            maxb = 2;
    }
    int grid = maxb * 256;               // 256 CUs on MI355X
    if (grid > 1024) grid = 1024;        // cap: keeps grid.sync cheap, >= 628 GEMM tiles

    void* args[] = { (void*)&a };
    hipLaunchCooperativeKernel(mega, dim3(grid), dim3(256), args, 0, stream);
}

// Round 2
// 180.090 us; speedup vs baseline: 2.9989x; 2.9989x over previous
//
#include <hip/hip_runtime.h>
#include <hip/hip_bf16.h>

#define N_NODES 10000
#define DIM 512
#define NCLS 64
#define BM 64
#define BN 128
#define BK 64
#define ELLW 64

typedef __hip_bfloat16 bf16;
typedef unsigned short u16;
typedef unsigned int u32;
typedef __attribute__((ext_vector_type(8))) short short8;
typedef __attribute__((ext_vector_type(4))) float f32x4;

__device__ __forceinline__ float b2f(bf16 v) { return __bfloat162float(v); }
__device__ __forceinline__ float ldIn(const void* p, size_t i, int isb) {
    return isb ? b2f(((const bf16*)p)[i]) : ((const float*)p)[i];
}
__device__ __forceinline__ int getE(const int* ei, int is64, int flat) {
    return is64 ? ei[2 * (size_t)flat] : ei[flat];
}
__device__ __forceinline__ void load_lds16(const bf16* g, bf16* l) {
    __builtin_amdgcn_global_load_lds(
        (const __attribute__((address_space(1))) void*)g,
        (__attribute__((address_space(3))) void*)l, 16, 0, 0);
}
__device__ __forceinline__ float blo(u32 v) { union {u32 u; float f;} x; x.u = v << 16; return x.f; }
__device__ __forceinline__ float bhi(u32 v) { union {u32 u; float f;} x; x.u = v & 0xffff0000u; return x.f; }
__device__ __forceinline__ u16  f2b(float f) { bf16 h = __float2bfloat16(f); return *(u16*)&h; }

// ---- fused preamble: dtype sniff per block | x->bf16 | 3 weight transposes |
//      bias->f32 | ELL build. cursor pre-zeroed by hipMemsetAsync. ----
__global__ __launch_bounds__(256) void convert_all(
        const void* __restrict__ X, const void* __restrict__ W1,
        const void* __restrict__ W2, const void* __restrict__ Wc,
        const void* __restrict__ b1, const void* __restrict__ b2,
        const void* __restrict__ bc, const int* __restrict__ ei,
        int* __restrict__ cursor, int* __restrict__ ell,
        bf16* __restrict__ Xb, bf16* __restrict__ Wt1, bf16* __restrict__ Wt2,
        bf16* __restrict__ Wtc, float* __restrict__ bF1, float* __restrict__ bF2,
        float* __restrict__ bFc, int E) {
    __shared__ float tile[32][33];
    __shared__ int sflags[2];
    int b = blockIdx.x, t = threadIdx.x;

    // per-block dtype sniff (X first 256 u16 + edge col check; L2-hot)
    if (t < 64) {
        const u16* x16 = (const u16*)X;
        int cf = 0;
        #pragma unroll
        for (int j = 0; j < 4; j++) {
            int e = (x16[t * 4 + j] >> 7) & 0xFF;
            cf += (e >= 97 && e <= 157) ? 1 : 0;
        }
        #pragma unroll
        for (int o = 32; o > 0; o >>= 1) cf += __shfl_xor(cf, o, 64);
        int cz = (t < 32) ? ((ei[2 * t + 1] == 0) ? 1 : 0) : 0;
        #pragma unroll
        for (int o = 32; o > 0; o >>= 1) cz += __shfl_xor(cz, o, 64);
        if (t == 0) { sflags[0] = (cf >= 200) ? 1 : 0; sflags[1] = (cz >= 16) ? 1 : 0; }
    }
    __syncthreads();
    int isb = sflags[0], is64 = sflags[1];

    if (b < 2500) {                      // x: 8 elems/thread, 5.12M total
        int base = (b * 256 + t) * 8;
        bf16 o[8];
        if (isb) {
            *(uint4*)o = *(const uint4*)((const bf16*)X + base);
        } else {
            const float* Xf = (const float*)X + base;
            float4 v0 = *(const float4*)Xf, v1 = *(const float4*)(Xf + 4);
            o[0] = __float2bfloat16(v0.x); o[1] = __float2bfloat16(v0.y);
            o[2] = __float2bfloat16(v0.z); o[3] = __float2bfloat16(v0.w);
            o[4] = __float2bfloat16(v1.x); o[5] = __float2bfloat16(v1.y);
            o[6] = __float2bfloat16(v1.z); o[7] = __float2bfloat16(v1.w);
        }
        *(uint4*)&Xb[base] = *(uint4*)o;
    } else if (b < 3044) {               // W[K][N] -> Wt[N][K] (32x32 tiles)
        const void* W; bf16* Wt; int N; int bb = b - 2500;
        if (bb < 256)      { W = W1; Wt = Wt1; N = DIM; }
        else if (bb < 512) { W = W2; Wt = Wt2; N = DIM;  bb -= 256; }
        else               { W = Wc; Wt = Wtc; N = NCLS; bb -= 512; }
        int nt = N / 32;
        int n0 = (bb % nt) * 32, k0 = (bb / nt) * 32;
        int tx = t & 31, ty = t >> 5;
        for (int r = ty; r < 32; r += 8)
            tile[r][tx] = ldIn(W, (size_t)(k0 + r) * N + n0 + tx, isb);
        __syncthreads();
        for (int r = ty; r < 32; r += 8)
            Wt[(size_t)(n0 + r) * DIM + k0 + tx] = __float2bfloat16(tile[tx][r]);
    } else if (b == 3044) {              // biases -> f32 (1088 elems)
        for (int i = t; i < 2 * DIM + NCLS; i += 256) {
            if (i < DIM)            bF1[i] = ldIn(b1, i, isb);
            else if (i < 2 * DIM)   bF2[i - DIM] = ldIn(b2, i - DIM, isb);
            else                    bFc[i - 2 * DIM] = ldIn(bc, i - 2 * DIM, isb);
        }
    } else {                             // ELL build: one atomic per edge
        int e = (b - 3045) * 256 + t;
        if (e >= E) return;
        int s = getE(ei, is64, e), d = getE(ei, is64, E + e);
        if (s == d || (unsigned)s >= N_NODES || (unsigned)d >= N_NODES) return;
        int pos = atomicAdd(&cursor[d], 1);
        ell[d * ELLW + (pos & (ELLW - 1))] = s;
    }
}

// ---- MFMA GEMM: C[M,Nc](bf16) = (A @ Bt^T) * rsqrt(deg[row]+1).
//      64x128 tile, BK=64 — verbatim from the verified 192 us kernel. ----
__global__ __launch_bounds__(256) void gemm_mfma(
        const bf16* __restrict__ A, const bf16* __restrict__ Bt,
        bf16* __restrict__ C, int M, int Nc, int K,
        const int* __restrict__ deg) {
    __shared__ bf16 At[BM * BK];    // 8 KB
    __shared__ bf16 Bts[BN * BK];   // 16 KB
    int t = threadIdx.x;
    int w = t >> 6, l = t & 63;
    int bm = blockIdx.y * BM, bn = blockIdx.x * BN;
    int wn = w * 32;

    f32x4 acc[4][2] = {};
    int srow8 = l >> 3;          // 0..7 within 8-row chunk
    int sk8b  = (l & 7) * 8;     // k-offset of this lane's 16B

    for (int k0 = 0; k0 < K; k0 += BK) {
        __syncthreads();
        #pragma unroll
        for (int i = 0; i < 2; i++) {     // A: 8 chunks of 8 rows, 2 per wave
            int c = w * 2 + i;
            load_lds16(A + (size_t)(bm + c * 8 + srow8) * K + k0 + sk8b, &At[c * 512]);
        }
        #pragma unroll
        for (int i = 0; i < 4; i++) {     // B: 16 chunks, 4 per wave
            int c = w * 4 + i;
            load_lds16(Bt + (size_t)(bn + c * 8 + srow8) * K + k0 + sk8b, &Bts[c * 512]);
        }
        __syncthreads();

        #pragma unroll
        for (int kk = 0; kk < BK; kk += 32) {
            short8 af[4], bfr[2];
            #pragma unroll
            for (int i = 0; i < 4; i++)
                af[i] = *(const short8*)&At[(i * 16 + (l & 15)) * BK + kk + (l >> 4) * 8];
            #pragma unroll
            for (int j = 0; j < 2; j++)
                bfr[j] = *(const short8*)&Bts[(wn + j * 16 + (l & 15)) * BK + kk + (l >> 4) * 8];
            #pragma unroll
            for (int i = 0; i < 4; i++)
                #pragma unroll
                for (int j = 0; j < 2; j++)
                    acc[i][j] = __builtin_amdgcn_mfma_f32_16x16x32_bf16(
                                    af[i], bfr[j], acc[i][j], 0, 0, 0);
        }
    }

    // C/D map: col = lane&15, row = (lane>>4)*4 + reg
    int col = l & 15, rq = (l >> 4) * 4;
    #pragma unroll
    for (int i = 0; i < 4; i++) {
        #pragma unroll
        for (int r = 0; r < 4; r++) {
            int gm = bm + i * 16 + rq + r;
            if (gm >= M) continue;
            float rs = rsqrtf((float)deg[gm] + 1.0f);
            #pragma unroll
            for (int j = 0; j < 2; j++) {
                int gn = bn + wn + j * 16 + col;
                C[(size_t)gm * Nc + gn] = __float2bfloat16(acc[i][j][r] * rs);
            }
        }
    }
}

// ---- gather (ELL), XCD-affine column-chunked: chunk = bid&3 (128 cols, 2.56 MB
//      slice < 4 MB per-XCD L2; bid%8 XCD round-robin pins chunk c to XCDs {c,c+4}).
//      One wave per (node, chunk); lane covers 2 cols (dword loads, 256B/row). ----
__global__ __launch_bounds__(256) void gather_ell(
        const int* __restrict__ cursor, const int* __restrict__ ell,
        const bf16* __restrict__ Hs, const float* __restrict__ bias,
        bf16* __restrict__ Out, int relu) {
    int t = threadIdx.x;
    int w = t >> 6, lane = t & 63;
    int chunk = blockIdx.x & 3;
    int wid = (blockIdx.x >> 2) * 4 + w;
    if (wid >= N_NODES) return;
    int c0 = chunk * 128 + lane * 2;    // this lane's column pair
    int cnt0 = cursor[wid];
    int cnt = min(cnt0, ELLW);
    int idx = ell[wid * ELLW + lane];   // lane i holds edge-index i

    u32 v = *(const u32*)(Hs + (size_t)wid * DIM + c0);   // self-loop
    float a0 = blo(v), a1 = bhi(v);

    int e = 0;
    for (; e + 7 < cnt; e += 8) {
        u32 r[8];
        #pragma unroll
        for (int b = 0; b < 8; b++) {
            int s = __shfl(idx, e + b, 64);
            r[b] = *(const u32*)(Hs + (size_t)s * DIM + c0);
        }
        a0 += ((blo(r[0]) + blo(r[1])) + (blo(r[2]) + blo(r[3])))
            + ((blo(r[4]) + blo(r[5])) + (blo(r[6]) + blo(r[7])));
        a1 += ((bhi(r[0]) + bhi(r[1])) + (bhi(r[2]) + bhi(r[3])))
            + ((bhi(r[4]) + bhi(r[5])) + (bhi(r[6]) + bhi(r[7])));
    }
    for (; e < cnt; e++) {
        int s = __shfl(idx, e, 64);
        u32 rv = *(const u32*)(Hs + (size_t)s * DIM + c0);
        a0 += blo(rv); a1 += bhi(rv);
    }

    float ds = rsqrtf((float)cnt0 + 1.0f);
    float v0 = a0 * ds + bias[c0];
    float v1 = a1 * ds + bias[c0 + 1];
    if (relu) { v0 = fmaxf(v0, 0.0f); v1 = fmaxf(v1, 0.0f); }
    u32 o = (u32)f2b(v0) | ((u32)f2b(v1) << 16);
    *(u32*)(Out + (size_t)wid * DIM + c0) = o;
}

// ---- fused classifier + bias + log-softmax: one wave per 16 rows, no LDS ----
__global__ __launch_bounds__(64) void cls_lsm_kernel(
        const bf16* __restrict__ A, const bf16* __restrict__ Wct,
        const float* __restrict__ bias, float* __restrict__ out, int M) {
    int l = threadIdx.x;
    int row0 = blockIdx.x * 16;
    int q = l >> 4, col15 = l & 15;

    f32x4 acc[4] = {};
    #pragma unroll 4
    for (int k0 = 0; k0 < DIM; k0 += 32) {
        short8 af = *(const short8*)&A[(size_t)(row0 + col15) * DIM + k0 + q * 8];
        #pragma unroll
        for (int j = 0; j < 4; j++) {
            short8 bfr = *(const short8*)&Wct[(size_t)(j * 16 + col15) * DIM + k0 + q * 8];
            acc[j] = __builtin_amdgcn_mfma_f32_16x16x32_bf16(af, bfr, acc[j], 0, 0, 0);
        }
    }

    float bcol[4];
    #pragma unroll
    for (int j = 0; j < 4; j++) bcol[j] = bias[j * 16 + col15];

    #pragma unroll
    for (int r = 0; r < 4; r++) {
        int row = row0 + q * 4 + r;
        float v[4];
        #pragma unroll
        for (int j = 0; j < 4; j++) v[j] = acc[j][r] + bcol[j];
        float m = fmaxf(fmaxf(v[0], v[1]), fmaxf(v[2], v[3]));
        #pragma unroll
        for (int o = 8; o > 0; o >>= 1) m = fmaxf(m, __shfl_xor(m, o, 64));
        float s = __expf(v[0] - m) + __expf(v[1] - m) + __expf(v[2] - m) + __expf(v[3] - m);
        #pragma unroll
        for (int o = 8; o > 0; o >>= 1) s += __shfl_xor(s, o, 64);
        float lse = m + __logf(s);
        if (row < M) {
            #pragma unroll
            for (int j = 0; j < 4; j++) {
                out[(size_t)row * NCLS + j * 16 + col15] = v[j];
                out[(size_t)M * NCLS + (size_t)row * NCLS + j * 16 + col15] = v[j] - lse;
            }
        }
    }
}

extern "C" void kernel_launch(void* const* d_in, const int* in_sizes, int n_in,
                              void* d_out, int out_size, void* d_ws, size_t ws_size,
                              hipStream_t stream) {
    const void* x  = d_in[0];
    const int*  ei = (const int*)d_in[1];
    const void* W1 = d_in[2];
    const void* b1 = d_in[3];
    const void* W2 = d_in[4];
    const void* b2 = d_in[5];
    const void* Wc = d_in[6];
    const void* bc = d_in[7];
    float* out = (float*)d_out;
    int E = in_sizes[1] / 2;

    // workspace layout (~38 MB; A-operand buffers padded to 10240 rows)
    char* ws = (char*)d_ws;
    float* bF1    = (float*)ws;                      // 2 KB
    float* bF2    = (float*)(ws + 4096);             // 2 KB
    float* bFc    = (float*)(ws + 8192);             // 256 B
    int*   cursor = (int*)(ws + 65536);              // 40 KB
    int*   ell    = (int*)(ws + 131072);             // 2.56 MB
    bf16*  xb     = (bf16*) (ws + 4194304);          // 10240 rows x 512 bf16
    bf16*  Wt1    = (bf16*) (ws + 14680064);         // 512 KB
    bf16*  Wt2    = (bf16*) (ws + 15204352);         // 512 KB
    bf16*  Wct    = (bf16*) (ws + 15728640);         // 64 KB
    bf16*  B0     = (bf16*) (ws + 16777216);         // 10240 rows
    bf16*  B1     = (bf16*) (ws + 27262976);         // 10240 rows

    dim3 gg(DIM / BN, (N_NODES + BM - 1) / BM);      // (4, 157)
    int gConv = 3045 + (E + 255) / 256;

    // ---- preamble ----
    hipMemsetAsync(cursor, 0, N_NODES * sizeof(int), stream);
    convert_all<<<gConv, 256, 0, stream>>>(x, W1, W2, Wc, b1, b2, bc, ei,
                                           cursor, ell, xb, Wt1, Wt2, Wct,
                                           bF1, bF2, bFc, E);

    // ---- layer 1 ----
    gemm_mfma<<<gg, 256, 0, stream>>>(xb, Wt1, B0, N_NODES, DIM, DIM, cursor);
    gather_ell<<<N_NODES, 256, 0, stream>>>(cursor, ell, B0, bF1, B1, 1);

    // ---- layer 2 ----
    gemm_mfma<<<gg, 256, 0, stream>>>(B1, Wt2, B0, N_NODES, DIM, DIM, cursor);
    gather_ell<<<N_NODES, 256, 0, stream>>>(cursor, ell, B0, bF2, B1, 0);

    // ---- fused classifier + log-softmax ----
    cls_lsm_kernel<<<(N_NODES + 15) / 16, 64, 0, stream>>>(B1, Wct, bFc, out, N_NODES);
}

// Round 3
// 174.610 us; speedup vs baseline: 3.0930x; 1.0314x over previous
//
#include <hip/hip_runtime.h>
#include <hip/hip_bf16.h>

#define N_NODES 10000
#define DIM 512
#define NCLS 64
#define BM 64
#define BN 128
#define BK 64
#define ELLW 64

typedef __hip_bfloat16 bf16;
typedef unsigned short u16;
typedef unsigned int u32;
typedef __attribute__((ext_vector_type(8))) short short8;
typedef __attribute__((ext_vector_type(4))) float f32x4;

__device__ __forceinline__ float b2f(bf16 v) { return __bfloat162float(v); }
__device__ __forceinline__ float ldIn(const void* p, size_t i, int isb) {
    return isb ? b2f(((const bf16*)p)[i]) : ((const float*)p)[i];
}
__device__ __forceinline__ int getE(const int* ei, int is64, int flat) {
    return is64 ? ei[2 * (size_t)flat] : ei[flat];
}
__device__ __forceinline__ void load_lds16(const bf16* g, bf16* l) {
    __builtin_amdgcn_global_load_lds(
        (const __attribute__((address_space(1))) void*)g,
        (__attribute__((address_space(3))) void*)l, 16, 0, 0);
}
__device__ __forceinline__ float blo(u32 v) { union {u32 u; float f;} x; x.u = v << 16; return x.f; }
__device__ __forceinline__ float bhi(u32 v) { union {u32 u; float f;} x; x.u = v & 0xffff0000u; return x.f; }
__device__ __forceinline__ u16  f2b(float f) { bf16 h = __float2bfloat16(f); return *(u16*)&h; }

// ---- fused preamble: dtype sniff per block | x->bf16 | 3 weight transposes |
//      bias->f32 | ELL build. cursor pre-zeroed by hipMemsetAsync. ----
__global__ __launch_bounds__(256) void convert_all(
        const void* __restrict__ X, const void* __restrict__ W1,
        const void* __restrict__ W2, const void* __restrict__ Wc,
        const void* __restrict__ b1, const void* __restrict__ b2,
        const void* __restrict__ bc, const int* __restrict__ ei,
        int* __restrict__ cursor, int* __restrict__ ell,
        bf16* __restrict__ Xb, bf16* __restrict__ Wt1, bf16* __restrict__ Wt2,
        bf16* __restrict__ Wtc, float* __restrict__ bF1, float* __restrict__ bF2,
        float* __restrict__ bFc, int E) {
    __shared__ float tile[32][33];
    __shared__ int sflags[2];
    int b = blockIdx.x, t = threadIdx.x;

    // per-block dtype sniff (X first 256 u16 + edge col check; L2-hot)
    if (t < 64) {
        const u16* x16 = (const u16*)X;
        int cf = 0;
        #pragma unroll
        for (int j = 0; j < 4; j++) {
            int e = (x16[t * 4 + j] >> 7) & 0xFF;
            cf += (e >= 97 && e <= 157) ? 1 : 0;
        }
        #pragma unroll
        for (int o = 32; o > 0; o >>= 1) cf += __shfl_xor(cf, o, 64);
        int cz = (t < 32) ? ((ei[2 * t + 1] == 0) ? 1 : 0) : 0;
        #pragma unroll
        for (int o = 32; o > 0; o >>= 1) cz += __shfl_xor(cz, o, 64);
        if (t == 0) { sflags[0] = (cf >= 200) ? 1 : 0; sflags[1] = (cz >= 16) ? 1 : 0; }
    }
    __syncthreads();
    int isb = sflags[0], is64 = sflags[1];

    if (b < 2500) {                      // x: 8 elems/thread, 5.12M total
        int base = (b * 256 + t) * 8;
        bf16 o[8];
        if (isb) {
            *(uint4*)o = *(const uint4*)((const bf16*)X + base);
        } else {
            const float* Xf = (const float*)X + base;
            float4 v0 = *(const float4*)Xf, v1 = *(const float4*)(Xf + 4);
            o[0] = __float2bfloat16(v0.x); o[1] = __float2bfloat16(v0.y);
            o[2] = __float2bfloat16(v0.z); o[3] = __float2bfloat16(v0.w);
            o[4] = __float2bfloat16(v1.x); o[5] = __float2bfloat16(v1.y);
            o[6] = __float2bfloat16(v1.z); o[7] = __float2bfloat16(v1.w);
        }
        *(uint4*)&Xb[base] = *(uint4*)o;
    } else if (b < 3044) {               // W[K][N] -> Wt[N][K] (32x32 tiles)
        const void* W; bf16* Wt; int N; int bb = b - 2500;
        if (bb < 256)      { W = W1; Wt = Wt1; N = DIM; }
        else if (bb < 512) { W = W2; Wt = Wt2; N = DIM;  bb -= 256; }
        else               { W = Wc; Wt = Wtc; N = NCLS; bb -= 512; }
        int nt = N / 32;
        int n0 = (bb % nt) * 32, k0 = (bb / nt) * 32;
        int tx = t & 31, ty = t >> 5;
        for (int r = ty; r < 32; r += 8)
            tile[r][tx] = ldIn(W, (size_t)(k0 + r) * N + n0 + tx, isb);
        __syncthreads();
        for (int r = ty; r < 32; r += 8)
            Wt[(size_t)(n0 + r) * DIM + k0 + tx] = __float2bfloat16(tile[tx][r]);
    } else if (b == 3044) {              // biases -> f32 (1088 elems)
        for (int i = t; i < 2 * DIM + NCLS; i += 256) {
            if (i < DIM)            bF1[i] = ldIn(b1, i, isb);
            else if (i < 2 * DIM)   bF2[i - DIM] = ldIn(b2, i - DIM, isb);
            else                    bFc[i - 2 * DIM] = ldIn(bc, i - 2 * DIM, isb);
        }
    } else {                             // ELL build: one atomic per edge
        int e = (b - 3045) * 256 + t;
        if (e >= E) return;
        int s = getE(ei, is64, e), d = getE(ei, is64, E + e);
        if (s == d || (unsigned)s >= N_NODES || (unsigned)d >= N_NODES) return;
        int pos = atomicAdd(&cursor[d], 1);
        ell[d * ELLW + (pos & (ELLW - 1))] = s;
    }
}

// ---- MFMA GEMM: C[M,Nc](bf16) = (A @ Bt^T) * rsqrt(deg[row]+1).
//      64x128 tile, BK=64. This round:
//      (1) T2 swizzle — linear LDS dest (global_load_lds), inverse-swizzled
//          global source k-slot ^= row&7, same XOR on ds_read slot
//          (2 lanes/bank instead of 4; verified conflict-free + correct in r1 mega).
//      (2) T3-min 2-phase dbuf — stage next K-tile BEFORE compute of current,
//          ONE barrier per K-step; loads fly under MFMA issue.
//      (3) XCD-affine bijective tile map — each A-panel served by one XCD L2. ----
__global__ __launch_bounds__(256) void gemm_mfma(
        const bf16* __restrict__ A, const bf16* __restrict__ Bt,
        bf16* __restrict__ C, int M, int Nc, int K,
        const int* __restrict__ deg) {
    __shared__ bf16 At[2][BM * BK];     // 2 x 8 KB
    __shared__ bf16 Bts[2][BN * BK];    // 2 x 16 KB
    int t = threadIdx.x;
    int w = t >> 6, l = t & 63;

    // XCD-affine bijective tile map: 628 tiles -> 8 XCD chunks (4x79 + 4x78),
    // col-fast within a chunk so consecutive tiles share the A-panel.
    int bid = blockIdx.x;
    int xcd = bid & 7, i0 = bid >> 3;
    int tile = (xcd < 4 ? xcd * 79 : 316 + (xcd - 4) * 78) + i0;
    int bm = (tile >> 2) * BM, bn = (tile & 3) * BN;
    int wn = w * 32;

    f32x4 acc[4][2] = {};
    int srow8 = l >> 3;                    // row 0..7 within 8-row chunk
    int sk8b  = (((l & 7) ^ srow8) * 8);   // pre-swizzled source k-offset

    // prologue: stage K-tile 0 into buf 0
    #pragma unroll
    for (int i = 0; i < 2; i++) {
        int c = w * 2 + i;
        load_lds16(A + (size_t)(bm + c * 8 + srow8) * K + sk8b, &At[0][c * 512]);
    }
    #pragma unroll
    for (int i = 0; i < 4; i++) {
        int c = w * 4 + i;
        load_lds16(Bt + (size_t)(bn + c * 8 + srow8) * K + sk8b, &Bts[0][c * 512]);
    }
    __syncthreads();   // drains vmcnt: buf0 ready

    for (int k0 = 0; k0 < K; k0 += BK) {
        int cur = (k0 >> 6) & 1;
        if (k0 + BK < K) {                 // stage NEXT tile into other buf
            #pragma unroll
            for (int i = 0; i < 2; i++) {
                int c = w * 2 + i;
                load_lds16(A + (size_t)(bm + c * 8 + srow8) * K + k0 + BK + sk8b,
                           &At[cur ^ 1][c * 512]);
            }
            #pragma unroll
            for (int i = 0; i < 4; i++) {
                int c = w * 4 + i;
                load_lds16(Bt + (size_t)(bn + c * 8 + srow8) * K + k0 + BK + sk8b,
                           &Bts[cur ^ 1][c * 512]);
            }
        }
        #pragma unroll
        for (int kk = 0; kk < BK; kk += 32) {
            short8 af[4], bfr[2];
            int slot = (((kk >> 3) + (l >> 4)) ^ (l & 7)) * 8;  // swizzled read slot
            #pragma unroll
            for (int i = 0; i < 4; i++)
                af[i] = *(const short8*)&At[cur][(i * 16 + (l & 15)) * BK + slot];
            #pragma unroll
            for (int j = 0; j < 2; j++)
                bfr[j] = *(const short8*)&Bts[cur][(wn + j * 16 + (l & 15)) * BK + slot];
            #pragma unroll
            for (int i = 0; i < 4; i++)
                #pragma unroll
                for (int j = 0; j < 2; j++)
                    acc[i][j] = __builtin_amdgcn_mfma_f32_16x16x32_bf16(
                                    af[i], bfr[j], acc[i][j], 0, 0, 0);
        }
        __syncthreads();   // one barrier/K-step: drains stage, protects buffers
    }

    // C/D map: col = lane&15, row = (lane>>4)*4 + reg
    int col = l & 15, rq = (l >> 4) * 4;
    #pragma unroll
    for (int i = 0; i < 4; i++) {
        #pragma unroll
        for (int r = 0; r < 4; r++) {
            int gm = bm + i * 16 + rq + r;
            if (gm >= M) continue;
            float rs = rsqrtf((float)deg[gm] + 1.0f);
            #pragma unroll
            for (int j = 0; j < 2; j++) {
                int gn = bn + wn + j * 16 + col;
                C[(size_t)gm * Nc + gn] = __float2bfloat16(acc[i][j][r] * rs);
            }
        }
    }
}

// ---- gather (ELL), XCD-affine column-chunked: chunk = bid&3 (128 cols, 2.56 MB
//      slice < 4 MB per-XCD L2; bid%8 XCD round-robin pins chunk c to XCDs {c,c+4}).
//      One wave per (node, chunk); lane covers 2 cols (dword loads, 256B/row). ----
__global__ __launch_bounds__(256) void gather_ell(
        const int* __restrict__ cursor, const int* __restrict__ ell,
        const bf16* __restrict__ Hs, const float* __restrict__ bias,
        bf16* __restrict__ Out, int relu) {
    int t = threadIdx.x;
    int w = t >> 6, lane = t & 63;
    int chunk = blockIdx.x & 3;
    int wid = (blockIdx.x >> 2) * 4 + w;
    if (wid >= N_NODES) return;
    int c0 = chunk * 128 + lane * 2;    // this lane's column pair
    int cnt0 = cursor[wid];
    int cnt = min(cnt0, ELLW);
    int idx = ell[wid * ELLW + lane];   // lane i holds edge-index i

    u32 v = *(const u32*)(Hs + (size_t)wid * DIM + c0);   // self-loop
    float a0 = blo(v), a1 = bhi(v);

    int e = 0;
    for (; e + 7 < cnt; e += 8) {
        u32 r[8];
        #pragma unroll
        for (int b = 0; b < 8; b++) {
            int s = __shfl(idx, e + b, 64);
            r[b] = *(const u32*)(Hs + (size_t)s * DIM + c0);
        }
        a0 += ((blo(r[0]) + blo(r[1])) + (blo(r[2]) + blo(r[3])))
            + ((blo(r[4]) + blo(r[5])) + (blo(r[6]) + blo(r[7])));
        a1 += ((bhi(r[0]) + bhi(r[1])) + (bhi(r[2]) + bhi(r[3])))
            + ((bhi(r[4]) + bhi(r[5])) + (bhi(r[6]) + bhi(r[7])));
    }
    for (; e < cnt; e++) {
        int s = __shfl(idx, e, 64);
        u32 rv = *(const u32*)(Hs + (size_t)s * DIM + c0);
        a0 += blo(rv); a1 += bhi(rv);
    }

    float ds = rsqrtf((float)cnt0 + 1.0f);
    float v0 = a0 * ds + bias[c0];
    float v1 = a1 * ds + bias[c0 + 1];
    if (relu) { v0 = fmaxf(v0, 0.0f); v1 = fmaxf(v1, 0.0f); }
    u32 o = (u32)f2b(v0) | ((u32)f2b(v1) << 16);
    *(u32*)(Out + (size_t)wid * DIM + c0) = o;
}

// ---- fused classifier + bias + log-softmax: one wave per 16 rows, no LDS ----
__global__ __launch_bounds__(64) void cls_lsm_kernel(
        const bf16* __restrict__ A, const bf16* __restrict__ Wct,
        const float* __restrict__ bias, float* __restrict__ out, int M) {
    int l = threadIdx.x;
    int row0 = blockIdx.x * 16;
    int q = l >> 4, col15 = l & 15;

    f32x4 acc[4] = {};
    #pragma unroll 4
    for (int k0 = 0; k0 < DIM; k0 += 32) {
        short8 af = *(const short8*)&A[(size_t)(row0 + col15) * DIM + k0 + q * 8];
        #pragma unroll
        for (int j = 0; j < 4; j++) {
            short8 bfr = *(const short8*)&Wct[(size_t)(j * 16 + col15) * DIM + k0 + q * 8];
            acc[j] = __builtin_amdgcn_mfma_f32_16x16x32_bf16(af, bfr, acc[j], 0, 0, 0);
        }
    }

    float bcol[4];
    #pragma unroll
    for (int j = 0; j < 4; j++) bcol[j] = bias[j * 16 + col15];

    #pragma unroll
    for (int r = 0; r < 4; r++) {
        int row = row0 + q * 4 + r;
        float v[4];
        #pragma unroll
        for (int j = 0; j < 4; j++) v[j] = acc[j][r] + bcol[j];
        float m = fmaxf(fmaxf(v[0], v[1]), fmaxf(v[2], v[3]));
        #pragma unroll
        for (int o = 8; o > 0; o >>= 1) m = fmaxf(m, __shfl_xor(m, o, 64));
        float s = __expf(v[0] - m) + __expf(v[1] - m) + __expf(v[2] - m) + __expf(v[3] - m);
        #pragma unroll
        for (int o = 8; o > 0; o >>= 1) s += __shfl_xor(s, o, 64);
        float lse = m + __logf(s);
        if (row < M) {
            #pragma unroll
            for (int j = 0; j < 4; j++) {
                out[(size_t)row * NCLS + j * 16 + col15] = v[j];
                out[(size_t)M * NCLS + (size_t)row * NCLS + j * 16 + col15] = v[j] - lse;
            }
        }
    }
}

extern "C" void kernel_launch(void* const* d_in, const int* in_sizes, int n_in,
                              void* d_out, int out_size, void* d_ws, size_t ws_size,
                              hipStream_t stream) {
    const void* x  = d_in[0];
    const int*  ei = (const int*)d_in[1];
    const void* W1 = d_in[2];
    const void* b1 = d_in[3];
    const void* W2 = d_in[4];
    const void* b2 = d_in[5];
    const void* Wc = d_in[6];
    const void* bc = d_in[7];
    float* out = (float*)d_out;
    int E = in_sizes[1] / 2;

    // workspace layout (~38 MB; A-operand buffers padded to 10240 rows)
    char* ws = (char*)d_ws;
    float* bF1    = (float*)ws;                      // 2 KB
    float* bF2    = (float*)(ws + 4096);             // 2 KB
    float* bFc    = (float*)(ws + 8192);             // 256 B
    int*   cursor = (int*)(ws + 65536);              // 40 KB
    int*   ell    = (int*)(ws + 131072);             // 2.56 MB
    bf16*  xb     = (bf16*) (ws + 4194304);          // 10240 rows x 512 bf16
    bf16*  Wt1    = (bf16*) (ws + 14680064);         // 512 KB
    bf16*  Wt2    = (bf16*) (ws + 15204352);         // 512 KB
    bf16*  Wct    = (bf16*) (ws + 15728640);         // 64 KB
    bf16*  B0     = (bf16*) (ws + 16777216);         // 10240 rows
    bf16*  B1     = (bf16*) (ws + 27262976);         // 10240 rows

    int gConv = 3045 + (E + 255) / 256;
    const int GEMM_GRID = 628;                       // 157 row-panels x 4 col-tiles

    // ---- preamble ----
    hipMemsetAsync(cursor, 0, N_NODES * sizeof(int), stream);
    convert_all<<<gConv, 256, 0, stream>>>(x, W1, W2, Wc, b1, b2, bc, ei,
                                           cursor, ell, xb, Wt1, Wt2, Wct,
                                           bF1, bF2, bFc, E);

    // ---- layer 1 ----
    gemm_mfma<<<GEMM_GRID, 256, 0, stream>>>(xb, Wt1, B0, N_NODES, DIM, DIM, cursor);
    gather_ell<<<N_NODES, 256, 0, stream>>>(cursor, ell, B0, bF1, B1, 1);

    // ---- layer 2 ----
    gemm_mfma<<<GEMM_GRID, 256, 0, stream>>>(B1, Wt2, B0, N_NODES, DIM, DIM, cursor);
    gather_ell<<<N_NODES, 256, 0, stream>>>(cursor, ell, B0, bF2, B1, 0);

    // ---- fused classifier + log-softmax ----
    cls_lsm_kernel<<<(N_NODES + 15) / 16, 64, 0, stream>>>(B1, Wct, bFc, out, N_NODES);
}